// Round 13
// baseline (80.499 us; speedup 1.0000x reference)
//
#include <hip/hip_runtime.h>

#define B_   4
#define LQ_  256
#define LK_  512
#define DIN_ 512
#define H_   256
#define DV_  512

#define L2E 1.4426950408889634f   // log2(e)
// tanh(x) = 1 - 2/(e^{2x}+1);  e^{2(q+k)} = (e^q * e^k)^2.
// eq/ek = 2^clamp(proj*L2E, ±126): finite & nonzero -> no NaN; p*p
// over/underflow gives exact tanh saturation (rcp(inf)=0, rcp(1)=1).

// =====================================================================
// Kernel 1: proj PARTIAL GEMM (r9/r10 verified structure).
// tile 64 rows x 128 h x 128 d (d-split 4), 256 thr, micro 8r x 4h
// (1.5 B LDS per FMA). grid = Q:128 + K:256 = 384 blocks; dead K exit.
//  Q out: qpart[ds][(b,i)][h]   row-major
//  K out: ekTpart[ds][b][h][j]  transposed (coalesced j-reads in K2)
// =====================================================================
__global__ __launch_bounds__(256) void proj_partial_kernel(
    const float* __restrict__ Q, const float* __restrict__ K,
    const float* __restrict__ Wq, const float* __restrict__ Wk,
    const int* __restrict__ valid_lens,
    float* __restrict__ qpart, float* __restrict__ ekTpart) {
  __shared__ float xs[64][68];
  __shared__ float ws[64][132];

  const int blk = blockIdx.x;
  const bool isQ = blk < 128;
  int b, row0, h0, ds;
  if (isQ) {
    const int qi = blk;
    ds = qi & 3; h0 = ((qi >> 2) & 1) * 128;
    const int rt = qi >> 3;            // 0..15
    b = rt >> 2; row0 = (rt & 3) * 64;
  } else {
    const int u = blk - 128;
    ds = u & 3; h0 = ((u >> 2) & 1) * 128;
    const int rt = u >> 3;             // 0..31, batch-interleaved
    b = rt & 3; row0 = (rt >> 2) * 64;
    if (row0 >= valid_lens[b]) return; // dead K tile (uniform, before barriers)
  }
  const int L = isQ ? LQ_ : LK_;
  const float* __restrict__ X = (isQ ? Q : K) + ((size_t)(b * L + row0)) * DIN_ + ds * 128;
  const float* __restrict__ Wb = (isQ ? Wq : Wk) + (size_t)(ds * 128) * H_ + h0;

  const int t = threadIdx.x;
  const int hthr = t & 31;    // h = h0 + 4*hthr
  const int rthr = t >> 5;    // rows row0 + rthr*8 .. +7

  float acc[8][4];
#pragma unroll
  for (int r = 0; r < 8; ++r)
#pragma unroll
    for (int c = 0; c < 4; ++c) acc[r][c] = 0.f;

  for (int dd = 0; dd < 128; dd += 64) {
    __syncthreads();
#pragma unroll
    for (int u = 0; u < 4; ++u) {
      const int f = t + 256 * u;
      const int r = f >> 4, c4 = (f & 15) << 2;
      *(float4*)&xs[r][c4] = *(const float4*)&X[(size_t)r * DIN_ + dd + c4];
    }
#pragma unroll
    for (int u = 0; u < 8; ++u) {
      const int f = t + 256 * u;
      const int k = f >> 5, c4 = (f & 31) << 2;
      *(float4*)&ws[k][c4] = *(const float4*)&Wb[(size_t)(dd + k) * H_ + c4];
    }
    __syncthreads();

    for (int k = 0; k < 64; k += 8) {
      float4 w4[8];
#pragma unroll
      for (int k8 = 0; k8 < 8; ++k8)
        w4[k8] = *(const float4*)&ws[k + k8][4 * hthr];
#pragma unroll
      for (int rr = 0; rr < 8; ++rr) {
        const float4 xa = *(const float4*)&xs[rthr * 8 + rr][k];
        const float4 xb = *(const float4*)&xs[rthr * 8 + rr][k + 4];
        const float xv[8] = {xa.x, xa.y, xa.z, xa.w, xb.x, xb.y, xb.z, xb.w};
#pragma unroll
        for (int k8 = 0; k8 < 8; ++k8) {
          acc[rr][0] = fmaf(xv[k8], w4[k8].x, acc[rr][0]);
          acc[rr][1] = fmaf(xv[k8], w4[k8].y, acc[rr][1]);
          acc[rr][2] = fmaf(xv[k8], w4[k8].z, acc[rr][2]);
          acc[rr][3] = fmaf(xv[k8], w4[k8].w, acc[rr][3]);
        }
      }
    }
  }

  if (isQ) {
    float* dst = qpart + (size_t)ds * (B_ * LQ_ * H_);
#pragma unroll
    for (int rr = 0; rr < 8; ++rr) {
      const int row = row0 + rthr * 8 + rr;
      float4 o = {acc[rr][0], acc[rr][1], acc[rr][2], acc[rr][3]};
      *(float4*)&dst[(size_t)(b * LQ_ + row) * H_ + h0 + 4 * hthr] = o;
    }
  } else {
    float* dst = ekTpart + (size_t)ds * (B_ * H_ * LK_);
#pragma unroll
    for (int c = 0; c < 4; ++c) {
      const int h = h0 + 4 * hthr + c;
      float* p = &dst[((size_t)b * H_ + h) * LK_ + row0 + rthr * 8];
      float4 lo = {acc[0][c], acc[1][c], acc[2][c], acc[3][c]};
      float4 hi = {acc[4][c], acc[5][c], acc[6][c], acc[7][c]};
      *(float4*)p = lo;
      *(float4*)(p + 4) = hi;
    }
  }
}

// =====================================================================
// Kernel 2: FUSED combine+exp + scores + masked softmax + AV.
// block = (b, 4 q-rows), 512 thr, grid = B*(LQ/4) = 256 (b-interleaved).
//  phase 0: eq[4][256] built in LDS (sum 4 q-partials + exp); wsum.
//  phase 1: thread = j: kv = exp(sum of 4 ekT-partials) streamed with
//           coalesced loads (16 in flight per h-quad); 4 rcp-accum chains.
//  phase 2: block softmax over j (valid-masked).
//  phase 3: thread = v-col: AV with x8-unrolled V loads.
// =====================================================================
__global__ __launch_bounds__(512) void fused_attn_kernel(
    const float* __restrict__ qpart, const float* __restrict__ ekTpart,
    const float* __restrict__ wv, const int* __restrict__ valid_lens,
    const float* __restrict__ V, float* __restrict__ out) {
  __shared__ float eqs[4][260];
  __shared__ float4 p4s[LK_];
  __shared__ float redm[8][4], reds[8][4];
  __shared__ float wsum_s;

  const int blk = blockIdx.x;
  const int b  = blk & 3;
  const int i0 = (blk >> 2) * 4;
  const int vl = valid_lens[b];
  const int t = threadIdx.x;
  const int lane = t & 63, wave = t >> 6;

  // ---- phase 0: eq rows + wsum ----
  const size_t QN = (size_t)B_ * LQ_ * H_;
#pragma unroll
  for (int e = t; e < 4 * H_; e += 512) {
    const int i = e >> 8, h = e & 255;
    const size_t base = (size_t)(b * LQ_ + i0 + i) * H_ + h;
    const float v = qpart[base] + qpart[QN + base] +
                    qpart[2 * QN + base] + qpart[3 * QN + base];
    eqs[i][h] = exp2f(fminf(fmaxf(v * L2E, -126.f), 126.f));
  }
  if (t < 64) {
    float s = wv[t] + wv[t + 64] + wv[t + 128] + wv[t + 192];
#pragma unroll
    for (int off = 32; off; off >>= 1) s += __shfl_xor(s, off);
    if (t == 0) wsum_s = s;
  }
  __syncthreads();
  const float Wsum = wsum_s;

  // ---- phase 1: scores for j = t ----
  float s[4] = {-3.0e38f, -3.0e38f, -3.0e38f, -3.0e38f};
  const bool valid = t < vl;
  if (valid) {
    const size_t KN = (size_t)B_ * H_ * LK_;
    const float* __restrict__ kb = ekTpart + (size_t)b * H_ * LK_ + t;
    float a0 = 0.f, a1 = 0.f, a2 = 0.f, a3 = 0.f;
    for (int h = 0; h < H_; h += 4) {
      float kraw[4];
#pragma unroll
      for (int u = 0; u < 4; ++u) {            // 16 coalesced loads in flight
        const size_t o = (size_t)(h + u) * LK_;
        kraw[u] = kb[o] + kb[KN + o] + kb[2 * KN + o] + kb[3 * KN + o];
      }
      float kv[4];
#pragma unroll
      for (int u = 0; u < 4; ++u)
        kv[u] = exp2f(fminf(fmaxf(kraw[u] * L2E, -126.f), 126.f));
      const float4 w4 = *(const float4*)&wv[h];      // uniform scalar
      const float ww[4] = {w4.x, w4.y, w4.z, w4.w};
      const float4 q0 = *(const float4*)&eqs[0][h];  // LDS broadcast b128
      const float4 q1 = *(const float4*)&eqs[1][h];
      const float4 q2 = *(const float4*)&eqs[2][h];
      const float4 q3 = *(const float4*)&eqs[3][h];
      const float qq0[4] = {q0.x, q0.y, q0.z, q0.w};
      const float qq1[4] = {q1.x, q1.y, q1.z, q1.w};
      const float qq2[4] = {q2.x, q2.y, q2.z, q2.w};
      const float qq3[4] = {q3.x, q3.y, q3.z, q3.w};
#pragma unroll
      for (int u = 0; u < 4; ++u) {
        float p;
        p = qq0[u] * kv[u]; a0 = fmaf(ww[u], __builtin_amdgcn_rcpf(fmaf(p, p, 1.f)), a0);
        p = qq1[u] * kv[u]; a1 = fmaf(ww[u], __builtin_amdgcn_rcpf(fmaf(p, p, 1.f)), a1);
        p = qq2[u] * kv[u]; a2 = fmaf(ww[u], __builtin_amdgcn_rcpf(fmaf(p, p, 1.f)), a2);
        p = qq3[u] * kv[u]; a3 = fmaf(ww[u], __builtin_amdgcn_rcpf(fmaf(p, p, 1.f)), a3);
      }
    }
    s[0] = fmaf(-2.f, a0, Wsum);
    s[1] = fmaf(-2.f, a1, Wsum);
    s[2] = fmaf(-2.f, a2, Wsum);
    s[3] = fmaf(-2.f, a3, Wsum);
  }

  // ---- phase 2: masked softmax over j (block-wide) ----
  float m[4];
#pragma unroll
  for (int ii = 0; ii < 4; ++ii) m[ii] = s[ii];
#pragma unroll
  for (int off = 32; off; off >>= 1)
#pragma unroll
    for (int ii = 0; ii < 4; ++ii) m[ii] = fmaxf(m[ii], __shfl_xor(m[ii], off));
  if (lane == 0)
#pragma unroll
    for (int ii = 0; ii < 4; ++ii) redm[wave][ii] = m[ii];
  __syncthreads();
  float e[4], sum[4];
#pragma unroll
  for (int ii = 0; ii < 4; ++ii) {
    float mx = redm[0][ii];
#pragma unroll
    for (int w = 1; w < 8; ++w) mx = fmaxf(mx, redm[w][ii]);
    e[ii] = valid ? __expf(s[ii] - mx) : 0.f;
    sum[ii] = e[ii];
  }
#pragma unroll
  for (int off = 32; off; off >>= 1)
#pragma unroll
    for (int ii = 0; ii < 4; ++ii) sum[ii] += __shfl_xor(sum[ii], off);
  if (lane == 0)
#pragma unroll
    for (int ii = 0; ii < 4; ++ii) reds[wave][ii] = sum[ii];
  __syncthreads();
  {
    float4 pv;
    float tot[4];
#pragma unroll
    for (int ii = 0; ii < 4; ++ii) {
      tot[ii] = reds[0][ii];
#pragma unroll
      for (int w = 1; w < 8; ++w) tot[ii] += reds[w][ii];
    }
    pv.x = e[0] * __builtin_amdgcn_rcpf(tot[0]);
    pv.y = e[1] * __builtin_amdgcn_rcpf(tot[1]);
    pv.z = e[2] * __builtin_amdgcn_rcpf(tot[2]);
    pv.w = e[3] * __builtin_amdgcn_rcpf(tot[3]);
    p4s[t] = pv;
  }
  __syncthreads();

  // ---- phase 3: AV (thread = v-column) ----
  const float* __restrict__ Vb = V + (size_t)b * LK_ * DV_ + t;
  float a[4] = {0.f, 0.f, 0.f, 0.f};
  int j = 0;
  const int jv = vl & ~7;
  for (; j < jv; j += 8) {
    float v[8];
#pragma unroll
    for (int u = 0; u < 8; ++u) v[u] = Vb[(size_t)(j + u) * DV_];
#pragma unroll
    for (int u = 0; u < 8; ++u) {
      const float4 pp = p4s[j + u];
      a[0] = fmaf(pp.x, v[u], a[0]); a[1] = fmaf(pp.y, v[u], a[1]);
      a[2] = fmaf(pp.z, v[u], a[2]); a[3] = fmaf(pp.w, v[u], a[3]);
    }
  }
  for (; j < vl; ++j) {
    const float v = Vb[(size_t)j * DV_];
    const float4 pp = p4s[j];
    a[0] = fmaf(pp.x, v, a[0]); a[1] = fmaf(pp.y, v, a[1]);
    a[2] = fmaf(pp.z, v, a[2]); a[3] = fmaf(pp.w, v, a[3]);
  }
#pragma unroll
  for (int ii = 0; ii < 4; ++ii)
    out[(size_t)(b * LQ_ + i0 + ii) * DV_ + t] = a[ii];
}

extern "C" void kernel_launch(void* const* d_in, const int* in_sizes, int n_in,
                              void* d_out, int out_size, void* d_ws, size_t ws_size,
                              hipStream_t stream) {
  const float* queries    = (const float*)d_in[0];
  const float* keys       = (const float*)d_in[1];
  const float* values     = (const float*)d_in[2];
  const int*   valid_lens = (const int*)d_in[3];
  const float* Wq         = (const float*)d_in[4];
  const float* Wk         = (const float*)d_in[5];
  const float* wv         = (const float*)d_in[6];
  float* out = (float*)d_out;

  char* ws = (char*)d_ws;
  float* qpart   = (float*)ws;                          // 4 x 1 MB @ 0
  float* ekTpart = (float*)(ws + (size_t)(4 << 20));    // 4 x 2 MB @ 4 MB

  proj_partial_kernel<<<384, 256, 0, stream>>>(
      queries, keys, Wq, Wk, valid_lens, qpart, ekTpart);
  fused_attn_kernel<<<B_ * (LQ_ / 4), 512, 0, stream>>>(
      qpart, ekTpart, wv, valid_lens, values, out);
}

// Round 14
// 59.201 us; speedup vs baseline: 1.3598x; 1.3598x over previous
//
#include <hip/hip_runtime.h>

#define B_   4
#define LQ_  256
#define LK_  512
#define DIN_ 512
#define H_   256
#define DV_  512

#define L2E 1.4426950408889634f   // log2(e)
// tanh(x) = 1 - 2/(e^{2x}+1);  e^{2(q+k)} = (e^q * e^k)^2.
// eq/ek = 2^clamp(proj*L2E, ±126): finite & nonzero -> no NaN; p*p
// over/underflow gives exact tanh saturation (rcp(inf)=0, rcp(1)=1).

// =====================================================================
// Kernel 1: proj PARTIAL GEMM. 64 rows x 128 h tiles, 256 thr,
// micro 8r x 4h (1.5 B LDS/FMA). d-split: Q=4 (128d/block), K=8 (64d).
// grid = Q:128 + K:512 = 640 blocks (live ~415 = 1.6/CU); dead K exit.
//  Q out: qpart[ds4][(b,i)][h]    row-major
//  K out: ekTpart[ds8][b][h][j]   transposed
// =====================================================================
__global__ __launch_bounds__(256) void proj_partial_kernel(
    const float* __restrict__ Q, const float* __restrict__ K,
    const float* __restrict__ Wq, const float* __restrict__ Wk,
    const int* __restrict__ valid_lens,
    float* __restrict__ qpart, float* __restrict__ ekTpart) {
  __shared__ float xs[64][68];
  __shared__ float ws[64][132];

  const int blk = blockIdx.x;
  const bool isQ = blk < 128;
  int b, row0, h0, ds;
  if (isQ) {
    ds = blk & 3; h0 = ((blk >> 2) & 1) * 128;
    const int rt = blk >> 3;           // 0..15
    b = rt >> 2; row0 = (rt & 3) * 64;
  } else {
    const int u = blk - 128;
    ds = u & 7; h0 = ((u >> 3) & 1) * 128;
    const int rt = u >> 4;             // 0..31, batch-interleaved
    b = rt & 3; row0 = (rt >> 2) * 64;
    if (row0 >= valid_lens[b]) return; // dead K tile (uniform, before barriers)
  }
  const int L = isQ ? LQ_ : LK_;
  const int dspan = isQ ? 128 : 64;
  const float* __restrict__ X  = (isQ ? Q : K) + ((size_t)(b * L + row0)) * DIN_ + ds * dspan;
  const float* __restrict__ Wb = (isQ ? Wq : Wk) + (size_t)(ds * dspan) * H_ + h0;

  const int t = threadIdx.x;
  const int hthr = t & 31;    // h = h0 + 4*hthr
  const int rthr = t >> 5;    // rows row0 + rthr*8 .. +7

  float acc[8][4];
#pragma unroll
  for (int r = 0; r < 8; ++r)
#pragma unroll
    for (int c = 0; c < 4; ++c) acc[r][c] = 0.f;

  for (int dd = 0; dd < dspan; dd += 64) {
    __syncthreads();
    // stage X: 64 rows x 64 d = 1024 f4 / 256 thr = 4 each
#pragma unroll
    for (int u = 0; u < 4; ++u) {
      const int f = t + 256 * u;
      const int r = f >> 4, c4 = (f & 15) << 2;
      *(float4*)&xs[r][c4] = *(const float4*)&X[(size_t)r * DIN_ + dd + c4];
    }
    // stage W: 64 d x 128 h = 2048 f4 / 256 thr = 8 each
#pragma unroll
    for (int u = 0; u < 8; ++u) {
      const int f = t + 256 * u;
      const int k = f >> 5, c4 = (f & 31) << 2;
      *(float4*)&ws[k][c4] = *(const float4*)&Wb[(size_t)(dd + k) * H_ + c4];
    }
    __syncthreads();

    for (int k = 0; k < 64; k += 8) {
      float4 w4[8];
#pragma unroll
      for (int k8 = 0; k8 < 8; ++k8)
        w4[k8] = *(const float4*)&ws[k + k8][4 * hthr];
#pragma unroll
      for (int rr = 0; rr < 8; ++rr) {
        const float4 xa = *(const float4*)&xs[rthr * 8 + rr][k];
        const float4 xb = *(const float4*)&xs[rthr * 8 + rr][k + 4];
        const float xv[8] = {xa.x, xa.y, xa.z, xa.w, xb.x, xb.y, xb.z, xb.w};
#pragma unroll
        for (int k8 = 0; k8 < 8; ++k8) {
          acc[rr][0] = fmaf(xv[k8], w4[k8].x, acc[rr][0]);
          acc[rr][1] = fmaf(xv[k8], w4[k8].y, acc[rr][1]);
          acc[rr][2] = fmaf(xv[k8], w4[k8].z, acc[rr][2]);
          acc[rr][3] = fmaf(xv[k8], w4[k8].w, acc[rr][3]);
        }
      }
    }
  }

  if (isQ) {
    float* dst = qpart + (size_t)ds * (B_ * LQ_ * H_);
#pragma unroll
    for (int rr = 0; rr < 8; ++rr) {
      const int row = row0 + rthr * 8 + rr;
      float4 o = {acc[rr][0], acc[rr][1], acc[rr][2], acc[rr][3]};
      *(float4*)&dst[(size_t)(b * LQ_ + row) * H_ + h0 + 4 * hthr] = o;
    }
  } else {
    float* dst = ekTpart + (size_t)ds * (B_ * H_ * LK_);
#pragma unroll
    for (int c = 0; c < 4; ++c) {
      const int h = h0 + 4 * hthr + c;
      float* p = &dst[((size_t)b * H_ + h) * LK_ + row0 + rthr * 8];
      float4 lo = {acc[0][c], acc[1][c], acc[2][c], acc[3][c]};
      float4 hi = {acc[4][c], acc[5][c], acc[6][c], acc[7][c]};
      *(float4*)p = lo;
      *(float4*)(p + 4) = hi;
    }
  }
}

// =====================================================================
// Kernel 2: combine 8 ekT partials + exp.  ek[b][h][j] (float4 elementwise).
// grid = 131072 f4 / 512 = 256 blocks. Reads 16 MB (L2-hot), writes 2 MB.
// =====================================================================
__global__ __launch_bounds__(512) void combine_ek_kernel(
    const float* __restrict__ ekTpart, float* __restrict__ ek) {
  const int k4 = blockIdx.x * 512 + threadIdx.x;   // 0..131071
  const size_t KN4 = (size_t)B_ * H_ * LK_ / 4;
  const float4* src = (const float4*)ekTpart;
  float4 s = src[k4];
#pragma unroll
  for (int p = 1; p < 8; ++p) {
    const float4 v = src[p * KN4 + k4];
    s.x += v.x; s.y += v.y; s.z += v.z; s.w += v.w;
  }
  float4 o;
  o.x = exp2f(fminf(fmaxf(s.x * L2E, -126.f), 126.f));
  o.y = exp2f(fminf(fmaxf(s.y * L2E, -126.f), 126.f));
  o.z = exp2f(fminf(fmaxf(s.z * L2E, -126.f), 126.f));
  o.w = exp2f(fminf(fmaxf(s.w * L2E, -126.f), 126.f));
  ((float4*)ek)[k4] = o;
}

// =====================================================================
// Kernel 3: FUSED eq-combine + scores + masked softmax + AV.
// block = (b, 4 q-rows), 512 thr, grid = 256 (b-interleaved).
//  phase 0: eqs[4][256] (sum 4 q-partials + exp), wvs, wsum.
//  phase 1: h-SPLIT: thread (jj = t&255, ht = t>>8) computes partial
//           scores over its 128-h half for j=jj and j=jj+256 (latter
//           only when vl>256, block-uniform branch). ALL threads busy
//           for any vl. Partials combined via LDS ph[2][4][512].
//  phase 2: block softmax over j.  phase 3: AV, x8-unrolled V loads.
// =====================================================================
__global__ __launch_bounds__(512) void fused_attn_kernel(
    const float* __restrict__ qpart, const float* __restrict__ ek,
    const float* __restrict__ wv, const int* __restrict__ valid_lens,
    const float* __restrict__ V, float* __restrict__ out) {
  __shared__ float eqs[4][260];
  __shared__ float wvs[256];
  __shared__ float ph[2][4][512];
  __shared__ float4 p4s[LK_];
  __shared__ float redm[8][4], reds[8][4];
  __shared__ float wsum_s;

  const int blk = blockIdx.x;
  const int b  = blk & 3;
  const int i0 = (blk >> 2) * 4;
  const int vl = valid_lens[b];
  const int t = threadIdx.x;
  const int lane = t & 63, wave = t >> 6;

  // ---- phase 0 ----
  const size_t QN = (size_t)B_ * LQ_ * H_;
#pragma unroll
  for (int e = t; e < 4 * H_; e += 512) {
    const int i = e >> 8, h = e & 255;
    const size_t base = (size_t)(b * LQ_ + i0 + i) * H_ + h;
    const float v = qpart[base] + qpart[QN + base] +
                    qpart[2 * QN + base] + qpart[3 * QN + base];
    eqs[i][h] = exp2f(fminf(fmaxf(v * L2E, -126.f), 126.f));
  }
  if (t < 256) wvs[t] = wv[t];
  if (t < 64) {
    float s = wv[t] + wv[t + 64] + wv[t + 128] + wv[t + 192];
#pragma unroll
    for (int off = 32; off; off >>= 1) s += __shfl_xor(s, off);
    if (t == 0) wsum_s = s;
  }
  __syncthreads();
  const float Wsum = wsum_s;

  // ---- phase 1: h-split scores ----
  const int jj = t & 255;
  const int ht = t >> 8;               // wave-uniform
  const int hb = ht * 128;
  const float* __restrict__ ekb = ek + (size_t)b * H_ * LK_;
  float aA[4] = {0.f, 0.f, 0.f, 0.f};
  float aB[4] = {0.f, 0.f, 0.f, 0.f};
  if (vl > 256) {
    for (int hh = 0; hh < 128; hh += 4) {
      const int h = hb + hh;
      float eA[4], eB[4];
#pragma unroll
      for (int u = 0; u < 4; ++u) {            // 8 coalesced loads in flight
        eA[u] = ekb[(size_t)(h + u) * LK_ + jj];
        eB[u] = ekb[(size_t)(h + u) * LK_ + jj + 256];
      }
      const float4 w4 = *(const float4*)&wvs[h];
      const float ww[4] = {w4.x, w4.y, w4.z, w4.w};
#pragma unroll
      for (int i = 0; i < 4; ++i) {
        const float4 q4 = *(const float4*)&eqs[i][h];
        const float qq[4] = {q4.x, q4.y, q4.z, q4.w};
#pragma unroll
        for (int u = 0; u < 4; ++u) {
          float p = qq[u] * eA[u];
          aA[i] = fmaf(ww[u], __builtin_amdgcn_rcpf(fmaf(p, p, 1.f)), aA[i]);
          p = qq[u] * eB[u];
          aB[i] = fmaf(ww[u], __builtin_amdgcn_rcpf(fmaf(p, p, 1.f)), aB[i]);
        }
      }
    }
  } else {
    for (int hh = 0; hh < 128; hh += 8) {
      const int h = hb + hh;
      float eA[8];
#pragma unroll
      for (int u = 0; u < 8; ++u)
        eA[u] = ekb[(size_t)(h + u) * LK_ + jj];
      const float4 wa = *(const float4*)&wvs[h];
      const float4 wb = *(const float4*)&wvs[h + 4];
      const float ww[8] = {wa.x, wa.y, wa.z, wa.w, wb.x, wb.y, wb.z, wb.w};
#pragma unroll
      for (int i = 0; i < 4; ++i) {
        const float4 qa = *(const float4*)&eqs[i][h];
        const float4 qb = *(const float4*)&eqs[i][h + 4];
        const float qq[8] = {qa.x, qa.y, qa.z, qa.w, qb.x, qb.y, qb.z, qb.w};
#pragma unroll
        for (int u = 0; u < 8; ++u) {
          float p = qq[u] * eA[u];
          aA[i] = fmaf(ww[u], __builtin_amdgcn_rcpf(fmaf(p, p, 1.f)), aA[i]);
        }
      }
    }
  }
#pragma unroll
  for (int i = 0; i < 4; ++i) {
    ph[ht][i][jj]       = aA[i];
    ph[ht][i][jj + 256] = aB[i];
  }
  __syncthreads();

  // ---- phase 2: masked softmax over j = t ----
  const bool valid = t < vl;
  float s[4], m[4];
#pragma unroll
  for (int i = 0; i < 4; ++i) {
    s[i] = valid ? fmaf(-2.f, ph[0][i][t] + ph[1][i][t], Wsum) : -3.0e38f;
    m[i] = s[i];
  }
#pragma unroll
  for (int off = 32; off; off >>= 1)
#pragma unroll
    for (int i = 0; i < 4; ++i) m[i] = fmaxf(m[i], __shfl_xor(m[i], off));
  if (lane == 0)
#pragma unroll
    for (int i = 0; i < 4; ++i) redm[wave][i] = m[i];
  __syncthreads();
  float e[4], sum[4];
#pragma unroll
  for (int i = 0; i < 4; ++i) {
    float mx = redm[0][i];
#pragma unroll
    for (int w = 1; w < 8; ++w) mx = fmaxf(mx, redm[w][i]);
    e[i] = valid ? __expf(s[i] - mx) : 0.f;
    sum[i] = e[i];
  }
#pragma unroll
  for (int off = 32; off; off >>= 1)
#pragma unroll
    for (int i = 0; i < 4; ++i) sum[i] += __shfl_xor(sum[i], off);
  if (lane == 0)
#pragma unroll
    for (int i = 0; i < 4; ++i) reds[wave][i] = sum[i];
  __syncthreads();
  {
    float4 pv;
    float tot[4];
#pragma unroll
    for (int i = 0; i < 4; ++i) {
      tot[i] = reds[0][i];
#pragma unroll
      for (int w = 1; w < 8; ++w) tot[i] += reds[w][i];
    }
    pv.x = e[0] * __builtin_amdgcn_rcpf(tot[0]);
    pv.y = e[1] * __builtin_amdgcn_rcpf(tot[1]);
    pv.z = e[2] * __builtin_amdgcn_rcpf(tot[2]);
    pv.w = e[3] * __builtin_amdgcn_rcpf(tot[3]);
    p4s[t] = pv;
  }
  __syncthreads();

  // ---- phase 3: AV (thread = v-column) ----
  const float* __restrict__ Vb = V + (size_t)b * LK_ * DV_ + t;
  float a[4] = {0.f, 0.f, 0.f, 0.f};
  int j = 0;
  const int jv = vl & ~7;
  for (; j < jv; j += 8) {
    float v[8];
#pragma unroll
    for (int u = 0; u < 8; ++u) v[u] = Vb[(size_t)(j + u) * DV_];
#pragma unroll
    for (int u = 0; u < 8; ++u) {
      const float4 pp = p4s[j + u];
      a[0] = fmaf(pp.x, v[u], a[0]); a[1] = fmaf(pp.y, v[u], a[1]);
      a[2] = fmaf(pp.z, v[u], a[2]); a[3] = fmaf(pp.w, v[u], a[3]);
    }
  }
  for (; j < vl; ++j) {
    const float v = Vb[(size_t)j * DV_];
    const float4 pp = p4s[j];
    a[0] = fmaf(pp.x, v, a[0]); a[1] = fmaf(pp.y, v, a[1]);
    a[2] = fmaf(pp.z, v, a[2]); a[3] = fmaf(pp.w, v, a[3]);
  }
#pragma unroll
  for (int i = 0; i < 4; ++i)
    out[(size_t)(b * LQ_ + i0 + i) * DV_ + t] = a[i];
}

extern "C" void kernel_launch(void* const* d_in, const int* in_sizes, int n_in,
                              void* d_out, int out_size, void* d_ws, size_t ws_size,
                              hipStream_t stream) {
  const float* queries    = (const float*)d_in[0];
  const float* keys       = (const float*)d_in[1];
  const float* values     = (const float*)d_in[2];
  const int*   valid_lens = (const int*)d_in[3];
  const float* Wq         = (const float*)d_in[4];
  const float* Wk         = (const float*)d_in[5];
  const float* wv         = (const float*)d_in[6];
  float* out = (float*)d_out;

  char* ws = (char*)d_ws;
  float* qpart   = (float*)ws;                           // 4 x 1 MB @ 0
  float* ekTpart = (float*)(ws + (size_t)( 4 << 20));    // 8 x 2 MB @ 4 MB
  float* ek      = (float*)(ws + (size_t)(20 << 20));    // 2 MB     @ 20 MB

  proj_partial_kernel<<<640, 256, 0, stream>>>(
      queries, keys, Wq, Wk, valid_lens, qpart, ekTpart);
  combine_ek_kernel<<<256, 512, 0, stream>>>(ekTpart, ek);
  fused_attn_kernel<<<B_ * (LQ_ / 4), 512, 0, stream>>>(
      qpart, ek, wv, valid_lens, values, out);
}

// Round 15
// 52.471 us; speedup vs baseline: 1.5342x; 1.1283x over previous
//
#include <hip/hip_runtime.h>

#define B_   4
#define LQ_  256
#define LK_  512
#define DIN_ 512
#define H_   256
#define DV_  512

#define L2E 1.4426950408889634f   // log2(e)
// tanh(x) = 1 - 2/(e^{2x}+1);  e^{2(q+k)} = e^{2q} * e^{2k}.
// eq2 = 2^clamp(2q*L2E,±126), ek2 likewise: each finite & nonzero.
// product inf -> rcp 0 (tanh=+1 exact); product 0 -> rcp 1 (tanh=-1 exact).

// =====================================================================
// Kernel 1: proj PARTIAL GEMM (r14 structure). 64r x 128h tiles, 256 thr,
// micro 8r x 4h. d-split: Q=4, K=8. grid 640; dead K tiles exit.
//  Q out: qpart[ds4][(b,i)][h]   row-major
//  K out: ekTpart[ds8][b][h][j]  transposed
// =====================================================================
__global__ __launch_bounds__(256) void proj_partial_kernel(
    const float* __restrict__ Q, const float* __restrict__ K,
    const float* __restrict__ Wq, const float* __restrict__ Wk,
    const int* __restrict__ valid_lens,
    float* __restrict__ qpart, float* __restrict__ ekTpart) {
  __shared__ float xs[64][68];
  __shared__ float ws[64][132];

  const int blk = blockIdx.x;
  const bool isQ = blk < 128;
  int b, row0, h0, ds;
  if (isQ) {
    ds = blk & 3; h0 = ((blk >> 2) & 1) * 128;
    const int rt = blk >> 3;
    b = rt >> 2; row0 = (rt & 3) * 64;
  } else {
    const int u = blk - 128;
    ds = u & 7; h0 = ((u >> 3) & 1) * 128;
    const int rt = u >> 4;             // batch-interleaved
    b = rt & 3; row0 = (rt >> 2) * 64;
    if (row0 >= valid_lens[b]) return;
  }
  const int L = isQ ? LQ_ : LK_;
  const int dspan = isQ ? 128 : 64;
  const float* __restrict__ X  = (isQ ? Q : K) + ((size_t)(b * L + row0)) * DIN_ + ds * dspan;
  const float* __restrict__ Wb = (isQ ? Wq : Wk) + (size_t)(ds * dspan) * H_ + h0;

  const int t = threadIdx.x;
  const int hthr = t & 31;
  const int rthr = t >> 5;

  float acc[8][4];
#pragma unroll
  for (int r = 0; r < 8; ++r)
#pragma unroll
    for (int c = 0; c < 4; ++c) acc[r][c] = 0.f;

  for (int dd = 0; dd < dspan; dd += 64) {
    __syncthreads();
#pragma unroll
    for (int u = 0; u < 4; ++u) {
      const int f = t + 256 * u;
      const int r = f >> 4, c4 = (f & 15) << 2;
      *(float4*)&xs[r][c4] = *(const float4*)&X[(size_t)r * DIN_ + dd + c4];
    }
#pragma unroll
    for (int u = 0; u < 8; ++u) {
      const int f = t + 256 * u;
      const int k = f >> 5, c4 = (f & 31) << 2;
      *(float4*)&ws[k][c4] = *(const float4*)&Wb[(size_t)(dd + k) * H_ + c4];
    }
    __syncthreads();

    for (int k = 0; k < 64; k += 8) {
      float4 w4[8];
#pragma unroll
      for (int k8 = 0; k8 < 8; ++k8)
        w4[k8] = *(const float4*)&ws[k + k8][4 * hthr];
#pragma unroll
      for (int rr = 0; rr < 8; ++rr) {
        const float4 xa = *(const float4*)&xs[rthr * 8 + rr][k];
        const float4 xb = *(const float4*)&xs[rthr * 8 + rr][k + 4];
        const float xv[8] = {xa.x, xa.y, xa.z, xa.w, xb.x, xb.y, xb.z, xb.w};
#pragma unroll
        for (int k8 = 0; k8 < 8; ++k8) {
          acc[rr][0] = fmaf(xv[k8], w4[k8].x, acc[rr][0]);
          acc[rr][1] = fmaf(xv[k8], w4[k8].y, acc[rr][1]);
          acc[rr][2] = fmaf(xv[k8], w4[k8].z, acc[rr][2]);
          acc[rr][3] = fmaf(xv[k8], w4[k8].w, acc[rr][3]);
        }
      }
    }
  }

  if (isQ) {
    float* dst = qpart + (size_t)ds * (B_ * LQ_ * H_);
#pragma unroll
    for (int rr = 0; rr < 8; ++rr) {
      const int row = row0 + rthr * 8 + rr;
      float4 o = {acc[rr][0], acc[rr][1], acc[rr][2], acc[rr][3]};
      *(float4*)&dst[(size_t)(b * LQ_ + row) * H_ + h0 + 4 * hthr] = o;
    }
  } else {
    float* dst = ekTpart + (size_t)ds * (B_ * H_ * LK_);
#pragma unroll
    for (int c = 0; c < 4; ++c) {
      const int h = h0 + 4 * hthr + c;
      float* p = &dst[((size_t)b * H_ + h) * LK_ + row0 + rthr * 8];
      float4 lo = {acc[0][c], acc[1][c], acc[2][c], acc[3][c]};
      float4 hi = {acc[4][c], acc[5][c], acc[6][c], acc[7][c]};
      *(float4*)p = lo;
      *(float4*)(p + 4) = hi;
    }
  }
}

// =====================================================================
// Kernel 2: combine 8 ekT partials + SQUARED exp: ek2 = 2^clamp(2k*L2E,±126)
// =====================================================================
__global__ __launch_bounds__(512) void combine_ek_kernel(
    const float* __restrict__ ekTpart, float* __restrict__ ek2) {
  const int k4 = blockIdx.x * 512 + threadIdx.x;
  const size_t KN4 = (size_t)B_ * H_ * LK_ / 4;
  const float4* src = (const float4*)ekTpart;
  float4 s = src[k4];
#pragma unroll
  for (int p = 1; p < 8; ++p) {
    const float4 v = src[p * KN4 + k4];
    s.x += v.x; s.y += v.y; s.z += v.z; s.w += v.w;
  }
  float4 o;
  o.x = exp2f(fminf(fmaxf(s.x * (2.f * L2E), -126.f), 126.f));
  o.y = exp2f(fminf(fmaxf(s.y * (2.f * L2E), -126.f), 126.f));
  o.z = exp2f(fminf(fmaxf(s.z * (2.f * L2E), -126.f), 126.f));
  o.w = exp2f(fminf(fmaxf(s.w * (2.f * L2E), -126.f), 126.f));
  ((float4*)ek2)[k4] = o;
}

// =====================================================================
// Kernel 3: FUSED eq-combine + scores + masked softmax + AV.
// block = (b, 2 q-rows), 512 thr = 512 j. grid = 512 (2 blocks/CU),
// pairing swizzle: b = (blk&3)^(blk>>8) -> the 2 blocks a CU gets come
// from different batches (vl-straggler smoothing).
// Inner: fmaf(q2,k2,1) -> rcp -> fmaf  (2 VALU + 1 trans / element).
// =====================================================================
__global__ __launch_bounds__(512) void fused_attn_kernel(
    const float* __restrict__ qpart, const float* __restrict__ ek2,
    const float* __restrict__ wv, const int* __restrict__ valid_lens,
    const float* __restrict__ V, float* __restrict__ out) {
  __shared__ float eqs[2][260];
  __shared__ float wvs[256];
  __shared__ float2 p2s[LK_];
  __shared__ float redm[8][2], reds[8][2];
  __shared__ float wsum_s;

  const int blk = blockIdx.x;
  const int b  = (blk & 3) ^ ((blk >> 8) & 1);
  const int i0 = (blk >> 2) * 2;
  const int vl = valid_lens[b];
  const int t = threadIdx.x;
  const int lane = t & 63, wave = t >> 6;

  // ---- phase 0: eq2 rows (squared exp), wv stage, wsum ----
  const size_t QN = (size_t)B_ * LQ_ * H_;
  {
    const int i = t >> 8, h = t & 255;
    const size_t base = (size_t)(b * LQ_ + i0 + i) * H_ + h;
    const float v = qpart[base] + qpart[QN + base] +
                    qpart[2 * QN + base] + qpart[3 * QN + base];
    eqs[i][h] = exp2f(fminf(fmaxf(v * (2.f * L2E), -126.f), 126.f));
  }
  if (t < 256) wvs[t] = wv[t];
  if (t < 64) {
    float s = wv[t] + wv[t + 64] + wv[t + 128] + wv[t + 192];
#pragma unroll
    for (int off = 32; off; off >>= 1) s += __shfl_xor(s, off);
    if (t == 0) wsum_s = s;
  }
  __syncthreads();
  const float Wsum = wsum_s;

  // ---- phase 1: scores for j = t (2 rows) ----
  const bool valid = t < vl;
  float s[2] = {-3.0e38f, -3.0e38f};
  if (valid) {
    const float* __restrict__ kb = ek2 + (size_t)b * H_ * LK_ + t;
    float a0 = 0.f, a1 = 0.f;
    for (int h = 0; h < H_; h += 8) {
      float kv[8];
#pragma unroll
      for (int u = 0; u < 8; ++u)
        kv[u] = kb[(size_t)(h + u) * LK_];          // 8 coalesced loads in flight
      const float4 wa = *(const float4*)&wvs[h];
      const float4 wb = *(const float4*)&wvs[h + 4];
      const float ww[8] = {wa.x, wa.y, wa.z, wa.w, wb.x, wb.y, wb.z, wb.w};
      const float4 q0a = *(const float4*)&eqs[0][h];
      const float4 q0b = *(const float4*)&eqs[0][h + 4];
      const float4 q1a = *(const float4*)&eqs[1][h];
      const float4 q1b = *(const float4*)&eqs[1][h + 4];
      const float q0[8] = {q0a.x, q0a.y, q0a.z, q0a.w, q0b.x, q0b.y, q0b.z, q0b.w};
      const float q1[8] = {q1a.x, q1a.y, q1a.z, q1a.w, q1b.x, q1b.y, q1b.z, q1b.w};
#pragma unroll
      for (int u = 0; u < 8; ++u) {
        a0 = fmaf(ww[u], __builtin_amdgcn_rcpf(fmaf(q0[u], kv[u], 1.f)), a0);
        a1 = fmaf(ww[u], __builtin_amdgcn_rcpf(fmaf(q1[u], kv[u], 1.f)), a1);
      }
    }
    s[0] = fmaf(-2.f, a0, Wsum);
    s[1] = fmaf(-2.f, a1, Wsum);
  }

  // ---- phase 2: masked softmax over j ----
  float m[2] = {s[0], s[1]};
#pragma unroll
  for (int off = 32; off; off >>= 1)
#pragma unroll
    for (int i = 0; i < 2; ++i) m[i] = fmaxf(m[i], __shfl_xor(m[i], off));
  if (lane == 0)
#pragma unroll
    for (int i = 0; i < 2; ++i) redm[wave][i] = m[i];
  __syncthreads();
  float e[2], sum[2];
#pragma unroll
  for (int i = 0; i < 2; ++i) {
    float mx = redm[0][i];
#pragma unroll
    for (int w = 1; w < 8; ++w) mx = fmaxf(mx, redm[w][i]);
    e[i] = valid ? __expf(s[i] - mx) : 0.f;
    sum[i] = e[i];
  }
#pragma unroll
  for (int off = 32; off; off >>= 1)
#pragma unroll
    for (int i = 0; i < 2; ++i) sum[i] += __shfl_xor(sum[i], off);
  if (lane == 0)
#pragma unroll
    for (int i = 0; i < 2; ++i) reds[wave][i] = sum[i];
  __syncthreads();
  {
    float tot[2];
#pragma unroll
    for (int i = 0; i < 2; ++i) {
      tot[i] = reds[0][i];
#pragma unroll
      for (int w = 1; w < 8; ++w) tot[i] += reds[w][i];
    }
    float2 pv;
    pv.x = e[0] * __builtin_amdgcn_rcpf(tot[0]);
    pv.y = e[1] * __builtin_amdgcn_rcpf(tot[1]);
    p2s[t] = pv;
  }
  __syncthreads();

  // ---- phase 3: AV (thread = v-column), x8-unrolled V loads ----
  const float* __restrict__ Vb = V + (size_t)b * LK_ * DV_ + t;
  float a0 = 0.f, a1 = 0.f;
  int j = 0;
  const int jv = vl & ~7;
  for (; j < jv; j += 8) {
    float v[8];
#pragma unroll
    for (int u = 0; u < 8; ++u) v[u] = Vb[(size_t)(j + u) * DV_];
#pragma unroll
    for (int u = 0; u < 8; ++u) {
      const float2 pp = p2s[j + u];
      a0 = fmaf(pp.x, v[u], a0);
      a1 = fmaf(pp.y, v[u], a1);
    }
  }
  for (; j < vl; ++j) {
    const float v = Vb[(size_t)j * DV_];
    const float2 pp = p2s[j];
    a0 = fmaf(pp.x, v, a0);
    a1 = fmaf(pp.y, v, a1);
  }
  out[(size_t)(b * LQ_ + i0) * DV_ + t]     = a0;
  out[(size_t)(b * LQ_ + i0 + 1) * DV_ + t] = a1;
}

extern "C" void kernel_launch(void* const* d_in, const int* in_sizes, int n_in,
                              void* d_out, int out_size, void* d_ws, size_t ws_size,
                              hipStream_t stream) {
  const float* queries    = (const float*)d_in[0];
  const float* keys       = (const float*)d_in[1];
  const float* values     = (const float*)d_in[2];
  const int*   valid_lens = (const int*)d_in[3];
  const float* Wq         = (const float*)d_in[4];
  const float* Wk         = (const float*)d_in[5];
  const float* wv         = (const float*)d_in[6];
  float* out = (float*)d_out;

  char* ws = (char*)d_ws;
  float* qpart   = (float*)ws;                           // 4 x 1 MB @ 0
  float* ekTpart = (float*)(ws + (size_t)( 4 << 20));    // 8 x 2 MB @ 4 MB
  float* ek2     = (float*)(ws + (size_t)(20 << 20));    // 2 MB     @ 20 MB

  proj_partial_kernel<<<640, 256, 0, stream>>>(
      queries, keys, Wq, Wk, valid_lens, qpart, ekTpart);
  combine_ek_kernel<<<256, 512, 0, stream>>>(ekTpart, ek2);
  fused_attn_kernel<<<512, 512, 0, stream>>>(
      qpart, ek2, wv, valid_lens, values, out);
}